// Round 5
// baseline (258.885 us; speedup 1.0000x reference)
//
#include <hip/hip_runtime.h>
#include <hip/hip_bf16.h>
#include <cstdint>

typedef __attribute__((ext_vector_type(8))) __bf16 bf16x8;
typedef __attribute__((ext_vector_type(4))) __bf16 bf16x4;
typedef __attribute__((ext_vector_type(4))) float  f32x4;

#define N_IMG 3136   // 56*56
#define NB16  196    // 3136/16
#define CB8   56     // 448/8
#define P_CNT 2496   // 52*48 interior pixels
#define NDIR  34     // stencil directions

// stencil offsets dy*56+dx for RADIUS=5 (matches get_indices_of_pairs order)
__constant__ int c_offs[NDIR] = {
  1,2,3,4,
  52,53,54,55,56,57,58,59,60,
  108,109,110,111,112,113,114,115,116,
  165,166,167,168,169,170,171,
  222,223,224,225,226};

__device__ __forceinline__ void block_sync(){
  // raw barrier: LDS drained, vector-mem loads stay in flight across it
  asm volatile("s_waitcnt lgkmcnt(0)\n\ts_barrier" ::: "memory");
}

__device__ __forceinline__ float elu_f(float v){
  return v > 0.f ? v : expm1f(v);
}

// ---------------- weight f32->bf16 prep (one launch, 4 segments) -------------
__global__ __launch_bounds__(256) void cvt_weights(
    const float* __restrict__ w83, const float* __restrict__ w84,
    const float* __restrict__ w85, const float* __restrict__ w9,
    __bf16* __restrict__ o83, __bf16* __restrict__ o84,
    __bf16* __restrict__ o85, __bf16* __restrict__ o9)
{
  int i = blockIdx.x*256 + threadIdx.x;  // index in float4 units
  const float* src; __bf16* dst; int off;
  if      (i <   8192){ src=w83; dst=o83; off=i; }
  else if (i <  40960){ src=w84; dst=o84; off=i-8192; }
  else if (i < 303104){ src=w85; dst=o85; off=i-40960; }
  else if (i < 353280){ src=w9 ; dst=o9 ; off=i-303104; }
  else return;
  f32x4 v = ((const f32x4*)src)[off];
  bf16x4 o;
  o[0]=(__bf16)v[0]; o[1]=(__bf16)v[1]; o[2]=(__bf16)v[2]; o[3]=(__bf16)v[3];
  ((bf16x4*)dst)[off] = o;
}

// ---------------- feature GEMMs: y1[n,c] = elu(W[MT x KTOT] * X[KTOT x N]) ---
// n-split tiles (NT=32) -> 392 blocks fill all CUs; waves split M only.
// A (weights) frag-loaded direct from global (L2), prefetched ONE STEP AHEAD
// into alternating register sets; issue order per step keeps every wait a
// counted vmcnt (the X prefetch is never drained):
//   LOADA(s+1) -> STOREB(X(s)) -> LOADB(X(s+2)) -> barrier -> MFMA(s)
// B staged in XOR-swizzled LDS (granule g of row n at elem n*64 + ((g^(n&7))*8)).
// Output in MFMA-B-fragment layout: idx=(((b*196+n/16)*56+c/8)*16+n%16)*8+c%8
template<int MT, int KTOT, int MW, int NT>
__global__ __launch_bounds__(MW*64) void gemm_feat(
    const float* __restrict__ X, const __bf16* __restrict__ Wb,
    __bf16* __restrict__ y1, int c_off)
{
  constexpr int WG    = MW*64;
  constexpr int MI    = MT/(MW*16);      // m-frags per wave
  constexpr int NI    = NT/16;           // n-frags per wave
  constexpr int TPK   = WG/16;           // threads per 4-row k-group
  constexpr int NC    = NT/TPK;          // n-cols per staging thread
  constexpr int NSTEP = KTOT/64;
  static_assert(MI*MW*16 == MT, "");
  static_assert(NC==2 || NC==4, "");
  static_assert(NSTEP % 2 == 0, "");

  __shared__ __bf16 Blds[2][NT*64];      // [buf][n*64 + swizzled k]

  const int tid  = threadIdx.x;
  const int lane = tid & 63;
  const int wm   = tid >> 6;
  const int l15  = lane & 15;
  const int l4   = lane >> 4;
  const int b    = blockIdx.y;
  const int n0   = blockIdx.x * NT;
  const float* Xb = X + (size_t)b * KTOT * N_IMG;

  const int kg  = tid / TPK;             // 4-row k-group (0..15)
  const int nc0 = (tid % TPK) * NC;      // first staged n-col

  float b0[4*NC], b1[4*NC];
  bf16x8 a0[MI*2], a1[MI*2];
  f32x4 acc[MI][NI];
  const f32x4 fz = {0.f,0.f,0.f,0.f};
  #pragma unroll
  for (int mi=0; mi<MI; ++mi)
    #pragma unroll
    for (int ni=0; ni<NI; ++ni) acc[mi][ni] = fz;

#define LOADA(ar, t) { \
  _Pragma("unroll") \
  for (int _mi=0;_mi<MI;++_mi) \
    _Pragma("unroll") \
    for (int _kk=0;_kk<2;++_kk) \
      (ar)[_mi*2+_kk] = *(const bf16x8*)(Wb + (size_t)(wm*(MI*16)+_mi*16+l15)*KTOT + (t)*64 + _kk*32 + l4*8); \
  }

#define LOADB(arr, t) { \
  const float* _src = Xb + (size_t)((t)*64 + kg*4)*N_IMG + n0 + nc0; \
  _Pragma("unroll") \
  for (int _r=0;_r<4;++_r){ \
    if constexpr (NC==2) { float2 _t2 = *(const float2*)(_src + (size_t)_r*N_IMG); \
                           (arr)[_r*2]=_t2.x; (arr)[_r*2+1]=_t2.y; } \
    else { f32x4 _t4 = *(const f32x4*)(_src + (size_t)_r*N_IMG); \
           (arr)[_r*4]=_t4[0]; (arr)[_r*4+1]=_t4[1]; \
           (arr)[_r*4+2]=_t4[2]; (arr)[_r*4+3]=_t4[3]; } \
  } }

#define STOREB(arr, bsel) { \
  const int _g = kg>>1, _h = kg&1; \
  _Pragma("unroll") \
  for (int _j=0;_j<NC;++_j){ \
    const int _n = nc0 + _j; \
    bf16x4 _v; \
    _Pragma("unroll") \
    for (int _r=0;_r<4;++_r) _v[_r] = (__bf16)(arr)[_r*NC + _j]; \
    *(bf16x4*)&Blds[bsel][_n*64 + ((_g ^ (_n & 7))<<3) + _h*4] = _v; \
  } }

#define MFMAS(ar, bsel) { \
  _Pragma("unroll") \
  for (int _kk=0;_kk<2;++_kk) \
    _Pragma("unroll") \
    for (int _ni=0;_ni<NI;++_ni){ \
      const int _n = _ni*16 + l15; \
      bf16x8 _bv = *(const bf16x8*)&Blds[bsel][_n*64 + (((_kk*4+l4) ^ (_n & 7))<<3)]; \
      _Pragma("unroll") \
      for (int _mi=0;_mi<MI;++_mi) \
        acc[_mi][_ni] = __builtin_amdgcn_mfma_f32_16x16x32_bf16((ar)[_mi*2+_kk], _bv, acc[_mi][_ni], 0,0,0); \
    } }

  // prologue
  LOADB(b0, 0);
  LOADB(b1, 1);
  LOADA(a0, 0);
  for (int s=0; s<NSTEP; s+=2){
    // even phase: compute step s from buf0 / a0
    LOADA(a1, s+1);
    STOREB(b0, 0);                       // waits (counted) for X(s)
    if (s+2 < NSTEP) LOADB(b0, s+2);
    block_sync();
    MFMAS(a0, 0);                        // waits (counted) for a0
    // odd phase: compute step s+1 from buf1 / a1
    if (s+2 < NSTEP) LOADA(a0, s+2);
    STOREB(b1, 1);
    if (s+3 < NSTEP) LOADB(b1, s+3);
    block_sync();
    MFMAS(a1, 1);
  }
#undef LOADA
#undef LOADB
#undef STOREB
#undef MFMAS

  // ---- epilogue: elu + store to fragment layout ----
  #pragma unroll
  for (int mi=0; mi<MI; ++mi){
    const int c0 = c_off + wm*(MI*16) + mi*16 + l4*4;  // 4 consecutive channels
    const int cb = c0 >> 3;
    const int jj = c0 & 7;
    #pragma unroll
    for (int ni=0; ni<NI; ++ni){
      const int n = n0 + ni*16 + l15;
      size_t idx = ((((size_t)b*NB16 + (n>>4))*CB8 + cb)*16 + (n&15))*8 + jj;
      f32x4 a = acc[mi][ni];
      bf16x4 o;
      #pragma unroll
      for (int r=0;r<4;++r) o[r] = (__bf16)elu_f(a[r]);
      *(bf16x4*)(y1 + idx) = o;
    }
  }
}

// ---------------- output GEMM: x2[n, o] = elu(w9[448x448] * y1) -------------
// LDS-free, barrier-free: both operands frag-loaded direct (L2/L3-resident).
__global__ __launch_bounds__(256) void gemm_out(
    const __bf16* __restrict__ y1, const __bf16* __restrict__ w9b,
    __bf16* __restrict__ x2)
{
  const int nt = blockIdx.x, mt = blockIdx.y, b = blockIdx.z;
  const int tid = threadIdx.x;
  if (mt == 7){
    // zero the pad columns 448..511 of this n-tile
    const int row = tid >> 2, q = tid & 3;
    __bf16* p = x2 + ((size_t)b*N_IMG + nt*64 + row)*512 + 448 + q*16;
    uint4 z = {0u,0u,0u,0u};
    *(uint4*)p = z;
    *(uint4*)(p+8) = z;
    return;
  }
  const int lane = tid & 63, wid = tid >> 6;
  const int l15 = lane & 15, l4 = lane >> 4;
  // each wave owns one 16-col block of y1's fragment layout
  const __bf16* Bbase = y1 + ((size_t)b*NB16 + nt*4 + wid)*CB8*128;
  const __bf16* Abase = w9b + (size_t)(mt*64 + l15)*448 + l4*8;
  f32x4 acc[4];
  const f32x4 fz = {0.f,0.f,0.f,0.f};
  #pragma unroll
  for (int mi=0;mi<4;++mi) acc[mi] = fz;

  for (int s=0;s<7;++s){
    #pragma unroll
    for (int kk=0;kk<2;++kk){
      bf16x8 bv = *(const bf16x8*)(Bbase + (s*2+kk)*512 + lane*8);  // linear lane*16B
      #pragma unroll
      for (int mi=0;mi<4;++mi){
        bf16x8 av = *(const bf16x8*)(Abase + (size_t)mi*16*448 + s*64 + kk*32);
        acc[mi] = __builtin_amdgcn_mfma_f32_16x16x32_bf16(av, bv, acc[mi], 0,0,0);
      }
    }
  }
  #pragma unroll
  for (int mi=0;mi<4;++mi){
    const int o = mt*64 + mi*16 + l4*4;
    const int n = nt*64 + wid*16 + l15;
    f32x4 a = acc[mi];
    bf16x4 v;
    #pragma unroll
    for (int r=0;r<4;++r) v[r] = (__bf16)elu_f(a[r]);
    *(bf16x4*)(x2 + ((size_t)b*N_IMG + n)*512 + o) = v;
  }
}

// ---------------- affinity stencil: one wave per (b, p) ---------------------
__global__ __launch_bounds__(256) void affinity_kernel(
    const __bf16* __restrict__ x2, float* __restrict__ out)
{
  const int b = blockIdx.x;                 // b fastest -> each XCD sees one batch
  const int lane = threadIdx.x & 63, wid = threadIdx.x >> 6;
  const int p = blockIdx.y*4 + wid;
  const int from = (p/48)*56 + 4 + (p%48);
  const __bf16* xb = x2 + (size_t)b*N_IMG*512;
  bf16x8 ffv = *(const bf16x8*)(xb + (size_t)from*512 + lane*8);
  float ff[8];
  #pragma unroll
  for (int j=0;j<8;++j) ff[j] = (float)ffv[j];
  for (int d=0; d<NDIR; ++d){
    const int to = from + c_offs[d];
    bf16x8 ftv = *(const bf16x8*)(xb + (size_t)to*512 + lane*8);
    float s = 0.f;
    #pragma unroll
    for (int j=0;j<8;++j) s += fabsf(ff[j] - (float)ftv[j]);
    #pragma unroll
    for (int m=1;m<64;m<<=1) s += __shfl_xor(s, m, 64);
    if (lane == 0) out[((size_t)b*NDIR + d)*P_CNT + p] = expf(-s*(1.f/448.f));
  }
}

extern "C" void kernel_launch(void* const* d_in, const int* in_sizes, int n_in,
                              void* d_out, int out_size, void* d_ws, size_t ws_size,
                              hipStream_t stream)
{
  (void)in_sizes; (void)n_in; (void)out_size; (void)ws_size;
  const float* conv4 = (const float*)d_in[0];
  const float* conv5 = (const float*)d_in[1];
  const float* conv6 = (const float*)d_in[2];
  const float* w83   = (const float*)d_in[3];
  const float* w84   = (const float*)d_in[4];
  const float* w85   = (const float*)d_in[5];
  const float* w9    = (const float*)d_in[6];
  // ind_from / ind_to (d_in[7], d_in[8]) are recomputed on device (hardcoded stencil)
  float* out = (float*)d_out;
  char* ws = (char*)d_ws;
  // workspace layout
  __bf16* w83b = (__bf16*)(ws + 0);         //  64x512
  __bf16* w84b = (__bf16*)(ws + 65536);     // 128x1024
  __bf16* w85b = (__bf16*)(ws + 327680);    // 256x4096
  __bf16* w9b  = (__bf16*)(ws + 2424832);   // 448x448
  __bf16* y1   = (__bf16*)(ws + 2826240);   // 4*3136*448, fragment layout
  __bf16* x2   = (__bf16*)(ws + 14065664);  // 4*3136*512 (448 + zero pad)

  cvt_weights<<<1380, 256, 0, stream>>>(w83,w84,w85,w9, w83b,w84b,w85b,w9b);
  gemm_feat< 64,  512, 4, 32><<<dim3(98,4), 256, 0, stream>>>(conv4, w83b, y1, 0);
  gemm_feat<128, 1024, 4, 32><<<dim3(98,4), 256, 0, stream>>>(conv5, w84b, y1, 64);
  gemm_feat<256, 4096, 4, 32><<<dim3(98,4), 256, 0, stream>>>(conv6, w85b, y1, 192);
  gemm_out<<<dim3(49,8,4), 256, 0, stream>>>(y1, w9b, x2);
  affinity_kernel<<<dim3(4,624), 256, 0, stream>>>(x2, out);
}

// Round 6
// 195.237 us; speedup vs baseline: 1.3260x; 1.3260x over previous
//
#include <hip/hip_runtime.h>
#include <hip/hip_bf16.h>
#include <cstdint>

typedef __attribute__((ext_vector_type(8))) __bf16 bf16x8;
typedef __attribute__((ext_vector_type(4))) __bf16 bf16x4;
typedef __attribute__((ext_vector_type(4))) float  f32x4;

#define N_IMG 3136   // 56*56
#define NB16  196    // 3136/16
#define CB8   56     // 448/8
#define P_CNT 2496   // 52*48 interior pixels
#define NDIR  34     // stencil directions

// stencil offsets dy*56+dx for RADIUS=5 (matches get_indices_of_pairs order)
__constant__ int c_offs[NDIR] = {
  1,2,3,4,
  52,53,54,55,56,57,58,59,60,
  108,109,110,111,112,113,114,115,116,
  165,166,167,168,169,170,171,
  222,223,224,225,226};

__device__ __forceinline__ void block_sync(){
  // raw barrier: LDS drained, vector-mem loads stay in flight across it
  asm volatile("s_waitcnt lgkmcnt(0)\n\ts_barrier" ::: "memory");
}

__device__ __forceinline__ float elu_f(float v){
  return v > 0.f ? v : expm1f(v);
}

// ---------------- weight f32->bf16 prep (one launch, 4 segments) -------------
__global__ __launch_bounds__(256) void cvt_weights(
    const float* __restrict__ w83, const float* __restrict__ w84,
    const float* __restrict__ w85, const float* __restrict__ w9,
    __bf16* __restrict__ o83, __bf16* __restrict__ o84,
    __bf16* __restrict__ o85, __bf16* __restrict__ o9)
{
  int i = blockIdx.x*256 + threadIdx.x;  // index in float4 units
  const float* src; __bf16* dst; int off;
  if      (i <   8192){ src=w83; dst=o83; off=i; }
  else if (i <  40960){ src=w84; dst=o84; off=i-8192; }
  else if (i < 303104){ src=w85; dst=o85; off=i-40960; }
  else if (i < 353280){ src=w9 ; dst=o9 ; off=i-303104; }
  else return;
  f32x4 v = ((const f32x4*)src)[off];
  bf16x4 o;
  o[0]=(__bf16)v[0]; o[1]=(__bf16)v[1]; o[2]=(__bf16)v[2]; o[3]=(__bf16)v[3];
  ((bf16x4*)dst)[off] = o;
}

// ---------------- feature GEMMs: y1[n,c] = elu(W[MT x KTOT] * X[KTOT x N]) ---
// MI=1 per wave: wave wm owns ONE 16-row strip -> A-prefetch register set is
// tiny (16 VGPR for both sets), so the register allocator has no pressure to
// sink the prefetch loads down to their use (the R5 failure: VGPR=80 < the
// ~130 the written schedule needed -> LOADA sunk -> full latency exposed
// every step).  sched_barrier(0) additionally pins the issue point.
// Issue order per step keeps every wait a counted vmcnt:
//   LOADA(s+1) -> pin -> STOREB(X(s)) -> LOADB(X(s+2)) -> barrier -> MFMA(s)
// B staged in XOR-swizzled LDS (granule g of row n at elem n*64 + ((g^(n&7))*8)).
// Output in MFMA-B-fragment layout: idx=(((b*196+n/16)*56+c/8)*16+n%16)*8+c%8
template<int MT, int KTOT, int MW, int NT>
__global__ __launch_bounds__(MW*64) void gemm_feat(
    const float* __restrict__ X, const __bf16* __restrict__ Wb,
    __bf16* __restrict__ y1, int c_off)
{
  constexpr int WG    = MW*64;
  constexpr int MI    = MT/(MW*16);      // m-frags per wave (design: 1)
  constexpr int NI    = NT/16;           // n-frags per wave
  constexpr int TPK   = WG/16;           // threads per 4-row k-group
  constexpr int NC    = NT/TPK;          // n-cols per staging thread
  constexpr int NSTEP = KTOT/64;
  static_assert(MI*MW*16 == MT, "");
  static_assert(NC==1 || NC==2 || NC==4, "");
  static_assert(NSTEP % 2 == 0, "");

  __shared__ __bf16 Blds[2][NT*64];      // [buf][n*64 + swizzled k]

  const int tid  = threadIdx.x;
  const int lane = tid & 63;
  const int wm   = tid >> 6;
  const int l15  = lane & 15;
  const int l4   = lane >> 4;
  const int b    = blockIdx.y;
  const int n0   = blockIdx.x * NT;
  const float* Xb = X + (size_t)b * KTOT * N_IMG;

  const int kg  = tid / TPK;             // 4-row k-group (0..15)
  const int nc0 = (tid % TPK) * NC;      // first staged n-col

  float b0[4*NC], b1[4*NC];
  bf16x8 a0[MI*2], a1[MI*2];
  f32x4 acc[MI][NI];
  const f32x4 fz = {0.f,0.f,0.f,0.f};
  #pragma unroll
  for (int mi=0; mi<MI; ++mi)
    #pragma unroll
    for (int ni=0; ni<NI; ++ni) acc[mi][ni] = fz;

#define LOADA(ar, t) { \
  _Pragma("unroll") \
  for (int _mi=0;_mi<MI;++_mi) \
    _Pragma("unroll") \
    for (int _kk=0;_kk<2;++_kk) \
      (ar)[_mi*2+_kk] = *(const bf16x8*)(Wb + (size_t)(wm*(MI*16)+_mi*16+l15)*KTOT + (t)*64 + _kk*32 + l4*8); \
  }

#define LOADB(arr, t) { \
  const float* _src = Xb + (size_t)((t)*64 + kg*4)*N_IMG + n0 + nc0; \
  _Pragma("unroll") \
  for (int _r=0;_r<4;++_r){ \
    if constexpr (NC==1) { (arr)[_r] = _src[(size_t)_r*N_IMG]; } \
    else if constexpr (NC==2) { float2 _t2 = *(const float2*)(_src + (size_t)_r*N_IMG); \
                           (arr)[_r*2]=_t2.x; (arr)[_r*2+1]=_t2.y; } \
    else { f32x4 _t4 = *(const f32x4*)(_src + (size_t)_r*N_IMG); \
           (arr)[_r*4]=_t4[0]; (arr)[_r*4+1]=_t4[1]; \
           (arr)[_r*4+2]=_t4[2]; (arr)[_r*4+3]=_t4[3]; } \
  } }

#define STOREB(arr, bsel) { \
  const int _g = kg>>1, _h = kg&1; \
  _Pragma("unroll") \
  for (int _j=0;_j<NC;++_j){ \
    const int _n = nc0 + _j; \
    bf16x4 _v; \
    _Pragma("unroll") \
    for (int _r=0;_r<4;++_r) _v[_r] = (__bf16)(arr)[_r*NC + _j]; \
    *(bf16x4*)&Blds[bsel][_n*64 + ((_g ^ (_n & 7))<<3) + _h*4] = _v; \
  } }

#define MFMAS(ar, bsel) { \
  _Pragma("unroll") \
  for (int _kk=0;_kk<2;++_kk) \
    _Pragma("unroll") \
    for (int _ni=0;_ni<NI;++_ni){ \
      const int _n = _ni*16 + l15; \
      bf16x8 _bv = *(const bf16x8*)&Blds[bsel][_n*64 + (((_kk*4+l4) ^ (_n & 7))<<3)]; \
      _Pragma("unroll") \
      for (int _mi=0;_mi<MI;++_mi) \
        acc[_mi][_ni] = __builtin_amdgcn_mfma_f32_16x16x32_bf16((ar)[_mi*2+_kk], _bv, acc[_mi][_ni], 0,0,0); \
    } }

  // prologue
  LOADB(b0, 0);
  LOADB(b1, 1);
  LOADA(a0, 0);
  for (int s=0; s<NSTEP; s+=2){
    // even phase: compute step s from buf0 / a0
    LOADA(a1, s+1);
    __builtin_amdgcn_sched_barrier(0);   // pin prefetch issue point
    STOREB(b0, 0);                       // waits (counted) for X(s)
    if (s+2 < NSTEP) LOADB(b0, s+2);
    block_sync();
    MFMAS(a0, 0);                        // waits (counted) for a0
    // odd phase: compute step s+1 from buf1 / a1
    if (s+2 < NSTEP) LOADA(a0, s+2);
    __builtin_amdgcn_sched_barrier(0);
    STOREB(b1, 1);
    if (s+3 < NSTEP) LOADB(b1, s+3);
    block_sync();
    MFMAS(a1, 1);
  }
#undef LOADA
#undef LOADB
#undef STOREB
#undef MFMAS

  // ---- epilogue: elu + store to fragment layout ----
  #pragma unroll
  for (int mi=0; mi<MI; ++mi){
    const int c0 = c_off + wm*(MI*16) + mi*16 + l4*4;  // 4 consecutive channels
    const int cb = c0 >> 3;
    const int jj = c0 & 7;
    #pragma unroll
    for (int ni=0; ni<NI; ++ni){
      const int n = n0 + ni*16 + l15;
      size_t idx = ((((size_t)b*NB16 + (n>>4))*CB8 + cb)*16 + (n&15))*8 + jj;
      f32x4 a = acc[mi][ni];
      bf16x4 o;
      #pragma unroll
      for (int r=0;r<4;++r) o[r] = (__bf16)elu_f(a[r]);
      *(bf16x4*)(y1 + idx) = o;
    }
  }
}

// ---------------- output GEMM: x2[n, o] = elu(w9[448x448] * y1) -------------
// LDS-free, barrier-free: both operands frag-loaded direct (L2/L3-resident).
__global__ __launch_bounds__(256) void gemm_out(
    const __bf16* __restrict__ y1, const __bf16* __restrict__ w9b,
    __bf16* __restrict__ x2)
{
  const int nt = blockIdx.x, mt = blockIdx.y, b = blockIdx.z;
  const int tid = threadIdx.x;
  if (mt == 7){
    // zero the pad columns 448..511 of this n-tile
    const int row = tid >> 2, q = tid & 3;
    __bf16* p = x2 + ((size_t)b*N_IMG + nt*64 + row)*512 + 448 + q*16;
    uint4 z = {0u,0u,0u,0u};
    *(uint4*)p = z;
    *(uint4*)(p+8) = z;
    return;
  }
  const int lane = tid & 63, wid = tid >> 6;
  const int l15 = lane & 15, l4 = lane >> 4;
  // each wave owns one 16-col block of y1's fragment layout
  const __bf16* Bbase = y1 + ((size_t)b*NB16 + nt*4 + wid)*CB8*128;
  const __bf16* Abase = w9b + (size_t)(mt*64 + l15)*448 + l4*8;
  f32x4 acc[4];
  const f32x4 fz = {0.f,0.f,0.f,0.f};
  #pragma unroll
  for (int mi=0;mi<4;++mi) acc[mi] = fz;

  for (int s=0;s<7;++s){
    #pragma unroll
    for (int kk=0;kk<2;++kk){
      bf16x8 bv = *(const bf16x8*)(Bbase + (s*2+kk)*512 + lane*8);  // linear lane*16B
      #pragma unroll
      for (int mi=0;mi<4;++mi){
        bf16x8 av = *(const bf16x8*)(Abase + (size_t)mi*16*448 + s*64 + kk*32);
        acc[mi] = __builtin_amdgcn_mfma_f32_16x16x32_bf16(av, bv, acc[mi], 0,0,0);
      }
    }
  }
  #pragma unroll
  for (int mi=0;mi<4;++mi){
    const int o = mt*64 + mi*16 + l4*4;
    const int n = nt*64 + wid*16 + l15;
    f32x4 a = acc[mi];
    bf16x4 v;
    #pragma unroll
    for (int r=0;r<4;++r) v[r] = (__bf16)elu_f(a[r]);
    *(bf16x4*)(x2 + ((size_t)b*N_IMG + n)*512 + o) = v;
  }
}

// ---------------- affinity stencil: one wave per (b, p) ---------------------
__global__ __launch_bounds__(256) void affinity_kernel(
    const __bf16* __restrict__ x2, float* __restrict__ out)
{
  const int b = blockIdx.x;                 // b fastest -> each XCD sees one batch
  const int lane = threadIdx.x & 63, wid = threadIdx.x >> 6;
  const int p = blockIdx.y*4 + wid;
  const int from = (p/48)*56 + 4 + (p%48);
  const __bf16* xb = x2 + (size_t)b*N_IMG*512;
  bf16x8 ffv = *(const bf16x8*)(xb + (size_t)from*512 + lane*8);
  float ff[8];
  #pragma unroll
  for (int j=0;j<8;++j) ff[j] = (float)ffv[j];
  for (int d=0; d<NDIR; ++d){
    const int to = from + c_offs[d];
    bf16x8 ftv = *(const bf16x8*)(xb + (size_t)to*512 + lane*8);
    float s = 0.f;
    #pragma unroll
    for (int j=0;j<8;++j) s += fabsf(ff[j] - (float)ftv[j]);
    #pragma unroll
    for (int m=1;m<64;m<<=1) s += __shfl_xor(s, m, 64);
    if (lane == 0) out[((size_t)b*NDIR + d)*P_CNT + p] = expf(-s*(1.f/448.f));
  }
}

extern "C" void kernel_launch(void* const* d_in, const int* in_sizes, int n_in,
                              void* d_out, int out_size, void* d_ws, size_t ws_size,
                              hipStream_t stream)
{
  (void)in_sizes; (void)n_in; (void)out_size; (void)ws_size;
  const float* conv4 = (const float*)d_in[0];
  const float* conv5 = (const float*)d_in[1];
  const float* conv6 = (const float*)d_in[2];
  const float* w83   = (const float*)d_in[3];
  const float* w84   = (const float*)d_in[4];
  const float* w85   = (const float*)d_in[5];
  const float* w9    = (const float*)d_in[6];
  // ind_from / ind_to (d_in[7], d_in[8]) are recomputed on device (hardcoded stencil)
  float* out = (float*)d_out;
  char* ws = (char*)d_ws;
  // workspace layout
  __bf16* w83b = (__bf16*)(ws + 0);         //  64x512
  __bf16* w84b = (__bf16*)(ws + 65536);     // 128x1024
  __bf16* w85b = (__bf16*)(ws + 327680);    // 256x4096
  __bf16* w9b  = (__bf16*)(ws + 2424832);   // 448x448
  __bf16* y1   = (__bf16*)(ws + 2826240);   // 4*3136*448, fragment layout
  __bf16* x2   = (__bf16*)(ws + 14065664);  // 4*3136*512 (448 + zero pad)

  cvt_weights<<<1380, 256, 0, stream>>>(w83,w84,w85,w9, w83b,w84b,w85b,w9b);
  // MI=1 configs: wave count = MT/16, so WG = MT*4 threads
  gemm_feat< 64,  512,  4, 32><<<dim3(98,4), 256, 0, stream>>>(conv4, w83b, y1, 0);
  gemm_feat<128, 1024,  8, 32><<<dim3(98,4), 512, 0, stream>>>(conv5, w84b, y1, 64);
  gemm_feat<256, 4096, 16, 64><<<dim3(49,4), 1024, 0, stream>>>(conv6, w85b, y1, 192);
  gemm_out<<<dim3(49,8,4), 256, 0, stream>>>(y1, w9b, x2);
  affinity_kernel<<<dim3(4,624), 256, 0, stream>>>(x2, out);
}

// Round 7
// 193.593 us; speedup vs baseline: 1.3373x; 1.0085x over previous
//
#include <hip/hip_runtime.h>
#include <hip/hip_bf16.h>
#include <cstdint>

typedef __attribute__((ext_vector_type(8))) __bf16 bf16x8;
typedef __attribute__((ext_vector_type(4))) __bf16 bf16x4;
typedef __attribute__((ext_vector_type(4))) float  f32x4;

#define N_IMG 3136   // 56*56
#define NB16  196    // 3136/16
#define CB8   56     // 448/8
#define P_CNT 2496   // 52*48 interior pixels
#define NDIR  34     // stencil directions

// stencil offsets dy*56+dx for RADIUS=5 (matches get_indices_of_pairs order)
__constant__ int c_offs[NDIR] = {
  1,2,3,4,
  52,53,54,55,56,57,58,59,60,
  108,109,110,111,112,113,114,115,116,
  165,166,167,168,169,170,171,
  222,223,224,225,226};

__device__ __forceinline__ void block_sync(){
  // raw barrier: LDS drained, vector-mem loads stay in flight across it
  asm volatile("s_waitcnt lgkmcnt(0)\n\ts_barrier" ::: "memory");
}

__device__ __forceinline__ float elu_f(float v){
  return v > 0.f ? v : expm1f(v);
}

// ---------------- weight f32->bf16 prep (one launch, 4 segments) -------------
__global__ __launch_bounds__(256) void cvt_weights(
    const float* __restrict__ w83, const float* __restrict__ w84,
    const float* __restrict__ w85, const float* __restrict__ w9,
    __bf16* __restrict__ o83, __bf16* __restrict__ o84,
    __bf16* __restrict__ o85, __bf16* __restrict__ o9)
{
  int i = blockIdx.x*256 + threadIdx.x;  // index in float4 units
  const float* src; __bf16* dst; int off;
  if      (i <   8192){ src=w83; dst=o83; off=i; }
  else if (i <  40960){ src=w84; dst=o84; off=i-8192; }
  else if (i < 303104){ src=w85; dst=o85; off=i-40960; }
  else if (i < 353280){ src=w9 ; dst=o9 ; off=i-303104; }
  else return;
  f32x4 v = ((const f32x4*)src)[off];
  bf16x4 o;
  o[0]=(__bf16)v[0]; o[1]=(__bf16)v[1]; o[2]=(__bf16)v[2]; o[3]=(__bf16)v[3];
  ((bf16x4*)dst)[off] = o;
}

// ---------------- fused feature GEMMs -----------------------------------------
// y1[n,c] = elu(W[MT x KTOT] * X[KTOT x N]) for three segments in ONE dispatch:
//   blocks [0,196)   : conv6 * w85 (MT=256, K=4096, MI=2)
//   blocks [196,392) : conv5 * w84 (MT=128, K=1024, MI=1)
//   blocks [392,588) : conv4 * w83 (MT=64,  K=512,  MI=1, 4 compute waves)
// Uniform WG=512 (8 waves), NT=64 per tile.  A (weights) frag-loaded direct
// from global (L2), prefetched one step ahead into alternating register sets
// (MI<=2 keeps the prefetch set small so the allocator can't sink it; the
// sched_barrier(0) pins the issue point).  Issue order per step keeps every
// wait a counted vmcnt:
//   LOADA(s+1) -> pin -> STOREB(X(s)) -> LOADB(X(s+2)) -> barrier -> MFMA(s)
// B staged in XOR-swizzled LDS (granule g of row n at elem n*64 + ((g^(n&7))*8)).
// Output in MFMA-B-fragment layout: idx=(((b*196+n/16)*56+c/8)*16+n%16)*8+c%8
template<int MT, int KTOT, int MWA>
__device__ __forceinline__ void feat_body(
    const float* __restrict__ X, const __bf16* __restrict__ Wb,
    __bf16* __restrict__ y1, int c_off, int bidx,
    __bf16 (*Blds)[64*64])
{
  constexpr int MI    = MT/(MWA*16);     // m-frags per compute wave (1 or 2)
  constexpr int NI    = 4;               // n-frags per wave (all 64 n)
  constexpr int NSTEP = KTOT/64;
  static_assert(MI==1 || MI==2, "");
  static_assert(NSTEP % 2 == 0, "");

  const int tid  = threadIdx.x;          // 0..511
  const int lane = tid & 63;
  const int wm   = tid >> 6;             // 0..7
  const int l15  = lane & 15;
  const int l4   = lane >> 4;
  const int b    = bidx / 49;
  const int n0   = (bidx % 49) * 64;
  const float* Xb = X + (size_t)b * KTOT * N_IMG;

  const int kg  = tid >> 5;              // 4-row k-group (0..15)
  const int nc0 = (tid & 31) * 2;        // first staged n-col (NC=2)

  float b0[8], b1[8];
  bf16x8 a0[MI*2], a1[MI*2];
  f32x4 acc[MI][NI];
  const f32x4 fz = {0.f,0.f,0.f,0.f};
  #pragma unroll
  for (int mi=0; mi<MI; ++mi)
    #pragma unroll
    for (int ni=0; ni<NI; ++ni) acc[mi][ni] = fz;

#define LOADA(ar, t) { \
  if (wm < MWA) { \
    _Pragma("unroll") \
    for (int _mi=0;_mi<MI;++_mi) \
      _Pragma("unroll") \
      for (int _kk=0;_kk<2;++_kk) \
        (ar)[_mi*2+_kk] = *(const bf16x8*)(Wb + (size_t)(wm*(MI*16)+_mi*16+l15)*KTOT + (t)*64 + _kk*32 + l4*8); \
  } }

#define LOADB(arr, t) { \
  const float* _src = Xb + (size_t)((t)*64 + kg*4)*N_IMG + n0 + nc0; \
  _Pragma("unroll") \
  for (int _r=0;_r<4;++_r){ \
    float2 _t2 = *(const float2*)(_src + (size_t)_r*N_IMG); \
    (arr)[_r*2]=_t2.x; (arr)[_r*2+1]=_t2.y; \
  } }

#define STOREB(arr, bsel) { \
  const int _g = kg>>1, _h = kg&1; \
  _Pragma("unroll") \
  for (int _j=0;_j<2;++_j){ \
    const int _n = nc0 + _j; \
    bf16x4 _v; \
    _Pragma("unroll") \
    for (int _r=0;_r<4;++_r) _v[_r] = (__bf16)(arr)[_r*2 + _j]; \
    *(bf16x4*)&Blds[bsel][_n*64 + ((_g ^ (_n & 7))<<3) + _h*4] = _v; \
  } }

#define MFMAS(ar, bsel) { \
  if (wm < MWA) { \
    _Pragma("unroll") \
    for (int _kk=0;_kk<2;++_kk) \
      _Pragma("unroll") \
      for (int _ni=0;_ni<NI;++_ni){ \
        const int _n = _ni*16 + l15; \
        bf16x8 _bv = *(const bf16x8*)&Blds[bsel][_n*64 + (((_kk*4+l4) ^ (_n & 7))<<3)]; \
        _Pragma("unroll") \
        for (int _mi=0;_mi<MI;++_mi) \
          acc[_mi][_ni] = __builtin_amdgcn_mfma_f32_16x16x32_bf16((ar)[_mi*2+_kk], _bv, acc[_mi][_ni], 0,0,0); \
      } \
  } }

  // prologue
  LOADB(b0, 0);
  LOADB(b1, 1);
  LOADA(a0, 0);
  for (int s=0; s<NSTEP; s+=2){
    // even phase: compute step s from buf0 / a0
    LOADA(a1, s+1);
    __builtin_amdgcn_sched_barrier(0);   // pin prefetch issue point
    STOREB(b0, 0);                       // waits (counted) for X(s)
    if (s+2 < NSTEP) LOADB(b0, s+2);
    block_sync();
    MFMAS(a0, 0);                        // waits (counted) for a0
    // odd phase: compute step s+1 from buf1 / a1
    if (s+2 < NSTEP) LOADA(a0, s+2);
    __builtin_amdgcn_sched_barrier(0);
    STOREB(b1, 1);
    if (s+3 < NSTEP) LOADB(b1, s+3);
    block_sync();
    MFMAS(a1, 1);
  }
#undef LOADA
#undef LOADB
#undef STOREB
#undef MFMAS

  // ---- epilogue: elu + store to fragment layout ----
  if (wm < MWA){
    #pragma unroll
    for (int mi=0; mi<MI; ++mi){
      const int c0 = c_off + wm*(MI*16) + mi*16 + l4*4;  // 4 consecutive channels
      const int cb = c0 >> 3;
      const int jj = c0 & 7;
      #pragma unroll
      for (int ni=0; ni<NI; ++ni){
        const int n = n0 + ni*16 + l15;
        size_t idx = ((((size_t)b*NB16 + (n>>4))*CB8 + cb)*16 + (n&15))*8 + jj;
        f32x4 a = acc[mi][ni];
        bf16x4 o;
        #pragma unroll
        for (int r=0;r<4;++r) o[r] = (__bf16)elu_f(a[r]);
        *(bf16x4*)(y1 + idx) = o;
      }
    }
  }
}

__global__ __launch_bounds__(512) void gemm_feat_fused(
    const float* __restrict__ conv4, const float* __restrict__ conv5,
    const float* __restrict__ conv6,
    const __bf16* __restrict__ w83b, const __bf16* __restrict__ w84b,
    const __bf16* __restrict__ w85b, __bf16* __restrict__ y1)
{
  __shared__ __bf16 Blds[2][64*64];
  const int gid = blockIdx.x;
  if (gid < 196)       feat_body<256, 4096, 8>(conv6, w85b, y1, 192, gid,     Blds);
  else if (gid < 392)  feat_body<128, 1024, 8>(conv5, w84b, y1,  64, gid-196, Blds);
  else                 feat_body< 64,  512, 4>(conv4, w83b, y1,   0, gid-392, Blds);
}

// ---------------- output GEMM: x2[n, o] = elu(w9[448x448] * y1) -------------
// LDS-free, barrier-free: both operands frag-loaded direct (L2/L3-resident).
__global__ __launch_bounds__(256) void gemm_out(
    const __bf16* __restrict__ y1, const __bf16* __restrict__ w9b,
    __bf16* __restrict__ x2)
{
  const int nt = blockIdx.x, mt = blockIdx.y, b = blockIdx.z;
  const int tid = threadIdx.x;
  if (mt == 7){
    // zero the pad columns 448..511 of this n-tile
    const int row = tid >> 2, q = tid & 3;
    __bf16* p = x2 + ((size_t)b*N_IMG + nt*64 + row)*512 + 448 + q*16;
    uint4 z = {0u,0u,0u,0u};
    *(uint4*)p = z;
    *(uint4*)(p+8) = z;
    return;
  }
  const int lane = tid & 63, wid = tid >> 6;
  const int l15 = lane & 15, l4 = lane >> 4;
  // each wave owns one 16-col block of y1's fragment layout
  const __bf16* Bbase = y1 + ((size_t)b*NB16 + nt*4 + wid)*CB8*128;
  const __bf16* Abase = w9b + (size_t)(mt*64 + l15)*448 + l4*8;
  f32x4 acc[4];
  const f32x4 fz = {0.f,0.f,0.f,0.f};
  #pragma unroll
  for (int mi=0;mi<4;++mi) acc[mi] = fz;

  for (int s=0;s<7;++s){
    #pragma unroll
    for (int kk=0;kk<2;++kk){
      bf16x8 bv = *(const bf16x8*)(Bbase + (s*2+kk)*512 + lane*8);  // linear lane*16B
      #pragma unroll
      for (int mi=0;mi<4;++mi){
        bf16x8 av = *(const bf16x8*)(Abase + (size_t)mi*16*448 + s*64 + kk*32);
        acc[mi] = __builtin_amdgcn_mfma_f32_16x16x32_bf16(av, bv, acc[mi], 0,0,0);
      }
    }
  }
  #pragma unroll
  for (int mi=0;mi<4;++mi){
    const int o = mt*64 + mi*16 + l4*4;
    const int n = nt*64 + wid*16 + l15;
    f32x4 a = acc[mi];
    bf16x4 v;
    #pragma unroll
    for (int r=0;r<4;++r) v[r] = (__bf16)elu_f(a[r]);
    *(bf16x4*)(x2 + ((size_t)b*N_IMG + n)*512 + o) = v;
  }
}

// ---------------- affinity stencil: one wave per (b, p) ---------------------
__global__ __launch_bounds__(256) void affinity_kernel(
    const __bf16* __restrict__ x2, float* __restrict__ out)
{
  const int b = blockIdx.x;                 // b fastest -> each XCD sees one batch
  const int lane = threadIdx.x & 63, wid = threadIdx.x >> 6;
  const int p = blockIdx.y*4 + wid;
  const int from = (p/48)*56 + 4 + (p%48);
  const __bf16* xb = x2 + (size_t)b*N_IMG*512;
  bf16x8 ffv = *(const bf16x8*)(xb + (size_t)from*512 + lane*8);
  float ff[8];
  #pragma unroll
  for (int j=0;j<8;++j) ff[j] = (float)ffv[j];
  for (int d=0; d<NDIR; ++d){
    const int to = from + c_offs[d];
    bf16x8 ftv = *(const bf16x8*)(xb + (size_t)to*512 + lane*8);
    float s = 0.f;
    #pragma unroll
    for (int j=0;j<8;++j) s += fabsf(ff[j] - (float)ftv[j]);
    #pragma unroll
    for (int m=1;m<64;m<<=1) s += __shfl_xor(s, m, 64);
    if (lane == 0) out[((size_t)b*NDIR + d)*P_CNT + p] = expf(-s*(1.f/448.f));
  }
}

extern "C" void kernel_launch(void* const* d_in, const int* in_sizes, int n_in,
                              void* d_out, int out_size, void* d_ws, size_t ws_size,
                              hipStream_t stream)
{
  (void)in_sizes; (void)n_in; (void)out_size; (void)ws_size;
  const float* conv4 = (const float*)d_in[0];
  const float* conv5 = (const float*)d_in[1];
  const float* conv6 = (const float*)d_in[2];
  const float* w83   = (const float*)d_in[3];
  const float* w84   = (const float*)d_in[4];
  const float* w85   = (const float*)d_in[5];
  const float* w9    = (const float*)d_in[6];
  // ind_from / ind_to (d_in[7], d_in[8]) are recomputed on device (hardcoded stencil)
  float* out = (float*)d_out;
  char* ws = (char*)d_ws;
  // workspace layout
  __bf16* w83b = (__bf16*)(ws + 0);         //  64x512
  __bf16* w84b = (__bf16*)(ws + 65536);     // 128x1024
  __bf16* w85b = (__bf16*)(ws + 327680);    // 256x4096
  __bf16* w9b  = (__bf16*)(ws + 2424832);   // 448x448
  __bf16* y1   = (__bf16*)(ws + 2826240);   // 4*3136*448, fragment layout
  __bf16* x2   = (__bf16*)(ws + 14065664);  // 4*3136*512 (448 + zero pad)

  cvt_weights<<<1380, 256, 0, stream>>>(w83,w84,w85,w9, w83b,w84b,w85b,w9b);
  // fused g3+g2+g1: blocks [0,196)=conv6, [196,392)=conv5, [392,588)=conv4
  gemm_feat_fused<<<588, 512, 0, stream>>>(conv4, conv5, conv6, w83b, w84b, w85b, y1);
  gemm_out<<<dim3(49,8,4), 256, 0, stream>>>(y1, w9b, x2);
  affinity_kernel<<<dim3(4,624), 256, 0, stream>>>(x2, out);
}

// Round 9
// 189.777 us; speedup vs baseline: 1.3642x; 1.0201x over previous
//
#include <hip/hip_runtime.h>
#include <hip/hip_bf16.h>
#include <cstdint>

typedef __attribute__((ext_vector_type(8))) __bf16 bf16x8;
typedef __attribute__((ext_vector_type(4))) __bf16 bf16x4;
typedef __attribute__((ext_vector_type(4))) float  f32x4;

#define N_IMG 3136   // 56*56
#define NB16  196    // 3136/16
#define CB8   56     // 448/8
#define P_CNT 2496   // 52*48 interior pixels
#define NDIR  34     // stencil directions

// stencil offsets dy*56+dx for RADIUS=5 (matches get_indices_of_pairs order)
__constant__ int c_offs[NDIR] = {
  1,2,3,4,
  52,53,54,55,56,57,58,59,60,
  108,109,110,111,112,113,114,115,116,
  165,166,167,168,169,170,171,
  222,223,224,225,226};

__device__ __forceinline__ void block_sync(){
  // raw barrier: LDS drained, vector-mem loads stay in flight across it
  asm volatile("s_waitcnt lgkmcnt(0)\n\ts_barrier" ::: "memory");
}

__device__ __forceinline__ float elu_f(float v){
  return v > 0.f ? v : expm1f(v);
}

// ---------------- weight f32->bf16 prep (one launch, 4 segments) -------------
__global__ __launch_bounds__(256) void cvt_weights(
    const float* __restrict__ w83, const float* __restrict__ w84,
    const float* __restrict__ w85, const float* __restrict__ w9,
    __bf16* __restrict__ o83, __bf16* __restrict__ o84,
    __bf16* __restrict__ o85, __bf16* __restrict__ o9)
{
  int i = blockIdx.x*256 + threadIdx.x;  // index in float4 units
  const float* src; __bf16* dst; int off;
  if      (i <   8192){ src=w83; dst=o83; off=i; }
  else if (i <  40960){ src=w84; dst=o84; off=i-8192; }
  else if (i < 303104){ src=w85; dst=o85; off=i-40960; }
  else if (i < 353280){ src=w9 ; dst=o9 ; off=i-303104; }
  else return;
  f32x4 v = ((const f32x4*)src)[off];
  bf16x4 o;
  o[0]=(__bf16)v[0]; o[1]=(__bf16)v[1]; o[2]=(__bf16)v[2]; o[3]=(__bf16)v[3];
  ((bf16x4*)dst)[off] = o;
}

// ---------------- fused feature GEMMs -----------------------------------------
// y1[n,c] = elu(W[MT x KTOT] * X[KTOT x N]) for three segments in ONE dispatch:
//   blocks [0,196)   : conv6 * w85 (MT=256, K=4096, MI=2)   <- long pole, first
//   blocks [196,392) : conv5 * w84 (MT=128, K=1024, MI=1)
//   blocks [392,588) : conv4 * w83 (MT=64,  K=512,  MI=1, 4 compute waves)
// 4-step unrolled pipeline.  X has FOUR register tile-sets in flight (4-phase
// lead; breaks the latency fixed point R7 measured).  A has 2 sets with
// LOAD-AFTER-USE discipline (R8 bug: loading the set at phase top clobbered
// the fragments the same phase's MFMA was about to consume; now the reload of
// a set is issued right after its MFMAs, ~2 phases before next use).
// Issue order is monotone so every wait stays a counted vmcnt.
// B staged in XOR-swizzled LDS (granule g of row n at elem n*64 + ((g^(n&7))*8)).
// Output in MFMA-B-fragment layout: idx=(((b*196+n/16)*56+c/8)*16+n%16)*8+c%8
template<int MT, int KTOT, int MWA>
__device__ __forceinline__ void feat_body(
    const float* __restrict__ X, const __bf16* __restrict__ Wb,
    __bf16* __restrict__ y1, int c_off, int bidx,
    __bf16 (*Blds)[64*64])
{
  constexpr int MI    = MT/(MWA*16);     // m-frags per compute wave (1 or 2)
  constexpr int NI    = 4;               // n-frags per wave (all 64 n)
  constexpr int NSTEP = KTOT/64;
  static_assert(MI==1 || MI==2, "");
  static_assert(NSTEP % 4 == 0, "");

  const int tid  = threadIdx.x;          // 0..511
  const int lane = tid & 63;
  const int wm   = tid >> 6;             // 0..7
  const int l15  = lane & 15;
  const int l4   = lane >> 4;
  const int b    = bidx / 49;
  const int n0   = (bidx % 49) * 64;
  const float* Xb = X + (size_t)b * KTOT * N_IMG;

  const int kg  = tid >> 5;              // 4-row k-group (0..15)
  const int nc0 = (tid & 31) * 2;        // first staged n-col (NC=2)

  float b0[8], b1[8], b2[8], b3[8];
  bf16x8 a0[MI*2], a1[MI*2];
  f32x4 acc[MI][NI];
  const f32x4 fz = {0.f,0.f,0.f,0.f};
  #pragma unroll
  for (int mi=0; mi<MI; ++mi)
    #pragma unroll
    for (int ni=0; ni<NI; ++ni) acc[mi][ni] = fz;

#define LOADA(ar, t) { \
  if (wm < MWA && (t) < NSTEP) { \
    _Pragma("unroll") \
    for (int _mi=0;_mi<MI;++_mi) \
      _Pragma("unroll") \
      for (int _kk=0;_kk<2;++_kk) \
        (ar)[_mi*2+_kk] = *(const bf16x8*)(Wb + (size_t)(wm*(MI*16)+_mi*16+l15)*KTOT + (t)*64 + _kk*32 + l4*8); \
  } }

#define LOADB(arr, t) { \
  if ((t) < NSTEP) { \
    const float* _src = Xb + (size_t)((t)*64 + kg*4)*N_IMG + n0 + nc0; \
    _Pragma("unroll") \
    for (int _r=0;_r<4;++_r){ \
      float2 _t2 = *(const float2*)(_src + (size_t)_r*N_IMG); \
      (arr)[_r*2]=_t2.x; (arr)[_r*2+1]=_t2.y; \
    } \
  } }

#define STOREB(arr, bsel) { \
  const int _g = kg>>1, _h = kg&1; \
  _Pragma("unroll") \
  for (int _j=0;_j<2;++_j){ \
    const int _n = nc0 + _j; \
    bf16x4 _v; \
    _Pragma("unroll") \
    for (int _r=0;_r<4;++_r) _v[_r] = (__bf16)(arr)[_r*2 + _j]; \
    *(bf16x4*)&Blds[bsel][_n*64 + ((_g ^ (_n & 7))<<3) + _h*4] = _v; \
  } }

#define MFMAS(ar, bsel) { \
  if (wm < MWA) { \
    _Pragma("unroll") \
    for (int _kk=0;_kk<2;++_kk) \
      _Pragma("unroll") \
      for (int _ni=0;_ni<NI;++_ni){ \
        const int _n = _ni*16 + l15; \
        bf16x8 _bv = *(const bf16x8*)&Blds[bsel][_n*64 + (((_kk*4+l4) ^ (_n & 7))<<3)]; \
        _Pragma("unroll") \
        for (int _mi=0;_mi<MI;++_mi) \
          acc[_mi][_ni] = __builtin_amdgcn_mfma_f32_16x16x32_bf16((ar)[_mi*2+_kk], _bv, acc[_mi][_ni], 0,0,0); \
      } \
  } }

// one pipeline phase: stage X(s+J) to LDS, refill bJ with X(s+J+4), barrier,
// compute step (s+J) from A-set aUse, then (load-after-use) refill aUse with
// A(s+J+2) for its next turn two phases later.
#define PHASE(J, bJ, aUse) { \
  STOREB(bJ, (J)&1); \
  LOADB(bJ, s+(J)+4); \
  block_sync(); \
  MFMAS(aUse, (J)&1); \
  LOADA(aUse, s+(J)+2); \
  __builtin_amdgcn_sched_barrier(0); \
  }

  // prologue: 4 X tiles + 2 A steps in flight
  LOADB(b0, 0);
  LOADB(b1, 1);
  LOADB(b2, 2);
  LOADB(b3, 3);
  LOADA(a0, 0);
  LOADA(a1, 1);
  for (int s=0; s<NSTEP; s+=4){
    PHASE(0, b0, a0);   // uses a0=A(s),   then a0 <- A(s+2)
    PHASE(1, b1, a1);   // uses a1=A(s+1), then a1 <- A(s+3)
    PHASE(2, b2, a0);   // uses a0=A(s+2), then a0 <- A(s+4)
    PHASE(3, b3, a1);   // uses a1=A(s+3), then a1 <- A(s+5)
  }
#undef PHASE
#undef LOADA
#undef LOADB
#undef STOREB
#undef MFMAS

  // ---- epilogue: elu + store to fragment layout ----
  if (wm < MWA){
    #pragma unroll
    for (int mi=0; mi<MI; ++mi){
      const int c0 = c_off + wm*(MI*16) + mi*16 + l4*4;  // 4 consecutive channels
      const int cb = c0 >> 3;
      const int jj = c0 & 7;
      #pragma unroll
      for (int ni=0; ni<NI; ++ni){
        const int n = n0 + ni*16 + l15;
        size_t idx = ((((size_t)b*NB16 + (n>>4))*CB8 + cb)*16 + (n&15))*8 + jj;
        f32x4 a = acc[mi][ni];
        bf16x4 o;
        #pragma unroll
        for (int r=0;r<4;++r) o[r] = (__bf16)elu_f(a[r]);
        *(bf16x4*)(y1 + idx) = o;
      }
    }
  }
}

__global__ __launch_bounds__(512) void gemm_feat_fused(
    const float* __restrict__ conv4, const float* __restrict__ conv5,
    const float* __restrict__ conv6,
    const __bf16* __restrict__ w83b, const __bf16* __restrict__ w84b,
    const __bf16* __restrict__ w85b, __bf16* __restrict__ y1)
{
  __shared__ __bf16 Blds[2][64*64];
  const int gid = blockIdx.x;
  if (gid < 196)       feat_body<256, 4096, 8>(conv6, w85b, y1, 192, gid,     Blds);
  else if (gid < 392)  feat_body<128, 1024, 8>(conv5, w84b, y1,  64, gid-196, Blds);
  else                 feat_body< 64,  512, 4>(conv4, w83b, y1,   0, gid-392, Blds);
}

// ---------------- output GEMM: x2[n, o] = elu(w9[448x448] * y1) -------------
// LDS-free, barrier-free: both operands frag-loaded direct (L2/L3-resident).
__global__ __launch_bounds__(256) void gemm_out(
    const __bf16* __restrict__ y1, const __bf16* __restrict__ w9b,
    __bf16* __restrict__ x2)
{
  const int nt = blockIdx.x, mt = blockIdx.y, b = blockIdx.z;
  const int tid = threadIdx.x;
  if (mt == 7){
    // zero the pad columns 448..511 of this n-tile
    const int row = tid >> 2, q = tid & 3;
    __bf16* p = x2 + ((size_t)b*N_IMG + nt*64 + row)*512 + 448 + q*16;
    uint4 z = {0u,0u,0u,0u};
    *(uint4*)p = z;
    *(uint4*)(p+8) = z;
    return;
  }
  const int lane = tid & 63, wid = tid >> 6;
  const int l15 = lane & 15, l4 = lane >> 4;
  // each wave owns one 16-col block of y1's fragment layout
  const __bf16* Bbase = y1 + ((size_t)b*NB16 + nt*4 + wid)*CB8*128;
  const __bf16* Abase = w9b + (size_t)(mt*64 + l15)*448 + l4*8;
  f32x4 acc[4];
  const f32x4 fz = {0.f,0.f,0.f,0.f};
  #pragma unroll
  for (int mi=0;mi<4;++mi) acc[mi] = fz;

  for (int s=0;s<7;++s){
    #pragma unroll
    for (int kk=0;kk<2;++kk){
      bf16x8 bv = *(const bf16x8*)(Bbase + (s*2+kk)*512 + lane*8);  // linear lane*16B
      #pragma unroll
      for (int mi=0;mi<4;++mi){
        bf16x8 av = *(const bf16x8*)(Abase + (size_t)mi*16*448 + s*64 + kk*32);
        acc[mi] = __builtin_amdgcn_mfma_f32_16x16x32_bf16(av, bv, acc[mi], 0,0,0);
      }
    }
  }
  #pragma unroll
  for (int mi=0;mi<4;++mi){
    const int o = mt*64 + mi*16 + l4*4;
    const int n = nt*64 + wid*16 + l15;
    f32x4 a = acc[mi];
    bf16x4 v;
    #pragma unroll
    for (int r=0;r<4;++r) v[r] = (__bf16)elu_f(a[r]);
    *(bf16x4*)(x2 + ((size_t)b*N_IMG + n)*512 + o) = v;
  }
}

// ---------------- affinity stencil: one wave per (b, p) ---------------------
__global__ __launch_bounds__(256) void affinity_kernel(
    const __bf16* __restrict__ x2, float* __restrict__ out)
{
  const int b = blockIdx.x;                 // b fastest -> each XCD sees one batch
  const int lane = threadIdx.x & 63, wid = threadIdx.x >> 6;
  const int p = blockIdx.y*4 + wid;
  const int from = (p/48)*56 + 4 + (p%48);
  const __bf16* xb = x2 + (size_t)b*N_IMG*512;
  bf16x8 ffv = *(const bf16x8*)(xb + (size_t)from*512 + lane*8);
  float ff[8];
  #pragma unroll
  for (int j=0;j<8;++j) ff[j] = (float)ffv[j];
  for (int d=0; d<NDIR; ++d){
    const int to = from + c_offs[d];
    bf16x8 ftv = *(const bf16x8*)(xb + (size_t)to*512 + lane*8);
    float s = 0.f;
    #pragma unroll
    for (int j=0;j<8;++j) s += fabsf(ff[j] - (float)ftv[j]);
    #pragma unroll
    for (int m=1;m<64;m<<=1) s += __shfl_xor(s, m, 64);
    if (lane == 0) out[((size_t)b*NDIR + d)*P_CNT + p] = expf(-s*(1.f/448.f));
  }
}

extern "C" void kernel_launch(void* const* d_in, const int* in_sizes, int n_in,
                              void* d_out, int out_size, void* d_ws, size_t ws_size,
                              hipStream_t stream)
{
  (void)in_sizes; (void)n_in; (void)out_size; (void)ws_size;
  const float* conv4 = (const float*)d_in[0];
  const float* conv5 = (const float*)d_in[1];
  const float* conv6 = (const float*)d_in[2];
  const float* w83   = (const float*)d_in[3];
  const float* w84   = (const float*)d_in[4];
  const float* w85   = (const float*)d_in[5];
  const float* w9    = (const float*)d_in[6];
  // ind_from / ind_to (d_in[7], d_in[8]) are recomputed on device (hardcoded stencil)
  float* out = (float*)d_out;
  char* ws = (char*)d_ws;
  // workspace layout
  __bf16* w83b = (__bf16*)(ws + 0);         //  64x512
  __bf16* w84b = (__bf16*)(ws + 65536);     // 128x1024
  __bf16* w85b = (__bf16*)(ws + 327680);    // 256x4096
  __bf16* w9b  = (__bf16*)(ws + 2424832);   // 448x448
  __bf16* y1   = (__bf16*)(ws + 2826240);   // 4*3136*448, fragment layout
  __bf16* x2   = (__bf16*)(ws + 14065664);  // 4*3136*512 (448 + zero pad)

  cvt_weights<<<1380, 256, 0, stream>>>(w83,w84,w85,w9, w83b,w84b,w85b,w9b);
  // fused g3+g2+g1: blocks [0,196)=conv6, [196,392)=conv5, [392,588)=conv4
  gemm_feat_fused<<<588, 512, 0, stream>>>(conv4, conv5, conv6, w83b, w84b, w85b, y1);
  gemm_out<<<dim3(49,8,4), 256, 0, stream>>>(y1, w9b, x2);
  affinity_kernel<<<dim3(4,624), 256, 0, stream>>>(x2, out);
}